// Round 1
// baseline (479.412 us; speedup 1.0000x reference)
//
#include <hip/hip_runtime.h>
#include <math.h>

namespace {

constexpr int ROWS  = 128;   // rows per block
constexpr int BLOCK = 128;   // threads per block (1 thread = 1 row in compute phase)
constexpr int C     = 76;    // pred_reg columns: 12*4 + 1 + 12*2 + 3
constexpr int PER   = 12;    // PER_LOC_BIN_NUM
constexpr int NHB   = 12;    // NUM_HEAD_BIN

__global__ __launch_bounds__(BLOCK)
void decode_kernel(const float* __restrict__ roi,
                   const float* __restrict__ pred,
                   const float* __restrict__ anchor,
                   float* __restrict__ out,
                   int n)
{
    // pred tile: 128*76*4 = 38912 B. io tile (roi in / out result): 128*7*4 = 3584 B.
    // Total 42496 B LDS -> 3 blocks/CU.
    __shared__ float s_pred[ROWS * C];
    __shared__ float s_io[ROWS * 7];

    const int tid = threadIdx.x;
    const long long row0 = (long long)blockIdx.x * ROWS;
    const int rows = min(ROWS, (int)((long long)n - row0));

    // ---- stage pred tile: contiguous, fully coalesced float4 loads ----
    // row0*C*4 bytes is 16B-divisible (C=76 -> 304 B/row), rows*C always /4.
    const float4* gp4 = (const float4*)(pred + row0 * C);
    float4* sp4 = (float4*)s_pred;
    const int np4 = rows * (C / 4);
    for (int i = tid; i < np4; i += BLOCK) sp4[i] = gp4[i];

    // ---- stage roi tile (7 floats/row, contiguous) ----
    const float* groi = roi + row0 * 7;
    const int nrf = rows * 7;
    const int nr4 = nrf >> 2;                    // row0 multiple of 128 -> base 16B aligned
    const float4* gr4 = (const float4*)groi;
    float4* si4 = (float4*)s_io;
    for (int i = tid; i < nr4; i += BLOCK) si4[i] = gr4[i];
    for (int i = (nr4 << 2) + tid; i < nrf; i += BLOCK) s_io[i] = groi[i];

    __syncthreads();

    float r0 = 0.f, r1 = 0.f, r2 = 0.f, r3 = 0.f, r4 = 0.f, r5 = 0.f, r6 = 0.f;

    if (tid < rows) {
        // LDS row -> registers via ds_read_b128.
        // dword lane-stride 76 == 12 (mod 32): 8 consecutive lanes tile all 32
        // banks exactly with 4-dword granules -> conflict-free.
        float4 v4[C / 4];
        const float4* rp = (const float4*)(s_pred + tid * C);
        #pragma unroll
        for (int i = 0; i < C / 4; i++) v4[i] = rp[i];
        const float* v = (const float*)v4;

        // ---- x / z bin argmax (first-index ties => strict >), residual
        //      tracked at constant unrolled indices (no dynamic reg indexing)
        float bx = v[0];        int xb = 0; float xres = v[2 * PER + 0];
        float bz = v[PER + 0];  int zb = 0; float zres = v[3 * PER + 0];
        #pragma unroll
        for (int c2 = 1; c2 < PER; c2++) {
            if (v[c2] > bx)       { bx = v[c2];       xb = c2; xres = v[2 * PER + c2]; }
            if (v[PER + c2] > bz) { bz = v[PER + c2]; zb = c2; zres = v[3 * PER + c2]; }
        }
        float pos_x = (float)xb * 0.5f + 0.25f - 3.0f + xres * 0.5f;
        float pos_z = (float)zb * 0.5f + 0.25f - 3.0f + zres * 0.5f;

        // ---- pos_y (col 48) ----
        const float roi_x  = s_io[tid * 7 + 0];
        const float roi_y  = s_io[tid * 7 + 1];
        const float roi_z  = s_io[tid * 7 + 2];
        const float roi_ry = s_io[tid * 7 + 6];
        float pos_y = roi_y + v[48];

        // ---- heading: argmax over cols 49..60, residual 61..72 ----
        float br = v[49]; int rb = 0; float rres = v[61];
        #pragma unroll
        for (int c2 = 1; c2 < NHB; c2++) {
            if (v[49 + c2] > br) { br = v[49 + c2]; rb = c2; rres = v[61 + c2]; }
        }
        const float APC    = 0.52359877559829887f;   // 2*pi/12
        const float TWO_PI = 6.28318530717958648f;
        const float PI_F   = 3.14159265358979324f;
        float ry = (float)rb * APC + rres * (APC * 0.5f);
        ry = fmodf(ry, TWO_PI);
        if (ry < 0.f) ry += TWO_PI;        // floor-mod semantics of jnp %
        if (ry > PI_F) ry -= TWO_PI;

        // ---- hwl: cols 73..75 ----
        const float a0 = anchor[0], a1 = anchor[1], a2 = anchor[2];
        const float hh = v[73] * a0 + a0;
        const float ww = v[74] * a1 + a1;
        const float ll = v[75] * a2 + a2;

        // ---- rotate by -roi_ry ----
        const float cc = cosf(roi_ry);     // cos(-t) = cos(t)
        const float ss = -sinf(roi_ry);    // sin(-t)
        const float x_rot = pos_x * cc - pos_z * ss;
        const float z_rot = pos_x * ss + pos_z * cc;

        r0 = x_rot + roi_x;
        r1 = pos_y;
        r2 = z_rot + roi_z;
        r3 = hh; r4 = ww; r5 = ll;
        r6 = ry + roi_ry;
    }

    __syncthreads();   // all reads of s_io done before reuse as out staging

    if (tid < rows) {
        float* w = s_io + tid * 7;         // dword stride 7: conflict-free
        w[0] = r0; w[1] = r1; w[2] = r2; w[3] = r3; w[4] = r4; w[5] = r5; w[6] = r6;
    }

    __syncthreads();

    // ---- coalesced float4 store of the out tile ----
    float* gout = out + row0 * 7;
    float4* go4 = (float4*)gout;
    for (int i = tid; i < nr4; i += BLOCK) go4[i] = si4[i];
    for (int i = (nr4 << 2) + tid; i < nrf; i += BLOCK) gout[i] = s_io[i];
}

} // namespace

extern "C" void kernel_launch(void* const* d_in, const int* in_sizes, int n_in,
                              void* d_out, int out_size, void* d_ws, size_t ws_size,
                              hipStream_t stream) {
    const float* roi    = (const float*)d_in[0];   // (N,7) f32
    const float* pred   = (const float*)d_in[1];   // (N,76) f32
    const float* anchor = (const float*)d_in[2];   // (3,) f32
    float* out = (float*)d_out;                    // (N,7) f32

    const int n = in_sizes[0] / 7;
    const int grid = (n + ROWS - 1) / ROWS;
    decode_kernel<<<grid, BLOCK, 0, stream>>>(roi, pred, anchor, out, n);
}

// Round 2
// 424.133 us; speedup vs baseline: 1.1303x; 1.1303x over previous
//
#include <hip/hip_runtime.h>
#include <math.h>

namespace {

constexpr int ROWS  = 128;   // rows per block
constexpr int BLOCK = 128;   // 2 waves
constexpr int C     = 76;    // pred_reg columns: 12*4 + 1 + 12*2 + 3
constexpr int PER   = 12;
constexpr int NHB   = 12;
constexpr int NP4_FULL  = ROWS * C / 4;   // 2432 float4 (= 19 * 128)
constexpr int NIO4_FULL = ROWS * 7 / 4;   // 224 float4  (= 3.5 * 64)

// Async global->LDS, 16B per lane. HW writes lane l at (uniform lds base) + 16*l,
// so the LDS layout must be lane-contiguous in issue order (it is: flat tile).
__device__ __forceinline__ void gload_lds16(const float4* gsrc, float4* ldst) {
    __builtin_amdgcn_global_load_lds(
        (const __attribute__((address_space(1))) void*)gsrc,
        (__attribute__((address_space(3))) void*)ldst,
        16, 0, 0);
}

__global__ __launch_bounds__(BLOCK)
void decode_kernel(const float* __restrict__ roi,
                   const float* __restrict__ pred,
                   const float* __restrict__ anchor,
                   float* __restrict__ out,
                   int n)
{
    // 38912 B + 3584 B = 42.5 KB LDS -> 3 blocks/CU (6 waves/CU).
    __shared__ float s_pred[ROWS * C];
    __shared__ float s_io[ROWS * 7];

    const int tid  = threadIdx.x;
    const int wave = tid >> 6;
    const int lane = tid & 63;
    const long long row0 = (long long)blockIdx.x * ROWS;
    const int rows = min(ROWS, (int)((long long)n - row0));

    const float4* gp4 = (const float4*)(pred + row0 * C);   // 304 B/row -> 16B aligned
    const float4* gi4 = (const float4*)(roi + row0 * 7);    // row0 mult of 128 -> aligned
    float4* sp4 = (float4*)s_pred;
    float4* si4 = (float4*)s_io;

    if (rows == ROWS) {
        // ---- full tile: 19 + 2 unguarded async wave-chunk loads in flight ----
        #pragma unroll
        for (int k = 0; k < NP4_FULL / BLOCK; ++k) {          // 19
            const int off = k * BLOCK + wave * 64;            // wave-uniform
            gload_lds16(gp4 + off + lane, sp4 + off);
        }
        {
            const int off = wave * 64;                        // chunks 0,1
            gload_lds16(gi4 + off + lane, si4 + off);
            if (wave == 0) {
                gload_lds16(gi4 + 128 + lane, si4 + 128);     // chunk 2
            } else if (lane < NIO4_FULL - 192) {              // partial chunk 3 (32 lanes)
                gload_lds16(gi4 + 192 + lane, si4 + 192);
            }
        }
    } else {
        // ---- tail tile (N=1e6 -> rows=64 once): per-lane guarded ----
        const int np4  = rows * (C / 4);
        const int nio4 = (rows * 7) >> 2;                     // rows*7 may not be /4
        #pragma unroll
        for (int k = 0; k < NP4_FULL / BLOCK; ++k) {
            const int off = k * BLOCK + wave * 64;
            if (off + lane < np4) gload_lds16(gp4 + off + lane, sp4 + off);
        }
        #pragma unroll
        for (int k = 0; k < 2; ++k) {
            const int off = k * BLOCK + wave * 64;
            if (off + lane < nio4) gload_lds16(gi4 + off + lane, si4 + off);
        }
        // scalar tail of roi (rows*7 mod 4 floats)
        for (int i = (nio4 << 2) + tid; i < rows * 7; i += BLOCK)
            s_io[i] = roi[row0 * 7 + i];
    }

    const float a0 = anchor[0], a1 = anchor[1], a2 = anchor[2];  // overlaps async loads

    __syncthreads();   // drains vmcnt -> LDS tiles valid

    float r0 = 0.f, r1 = 0.f, r2 = 0.f, r3 = 0.f, r4 = 0.f, r5 = 0.f, r6 = 0.f;

    if (tid < rows) {
        float4 v4[C / 4];
        const float4* rp = (const float4*)(s_pred + tid * C);
        #pragma unroll
        for (int i = 0; i < C / 4; i++) v4[i] = rp[i];
        const float* v = (const float*)v4;

        // x / z argmax (first-index ties => strict >), residual at constant idx
        float bx = v[0];        int xb = 0; float xres = v[2 * PER + 0];
        float bz = v[PER + 0];  int zb = 0; float zres = v[3 * PER + 0];
        #pragma unroll
        for (int c2 = 1; c2 < PER; c2++) {
            if (v[c2] > bx)       { bx = v[c2];       xb = c2; xres = v[2 * PER + c2]; }
            if (v[PER + c2] > bz) { bz = v[PER + c2]; zb = c2; zres = v[3 * PER + c2]; }
        }
        float pos_x = (float)xb * 0.5f + 0.25f - 3.0f + xres * 0.5f;
        float pos_z = (float)zb * 0.5f + 0.25f - 3.0f + zres * 0.5f;

        const float roi_x  = s_io[tid * 7 + 0];
        const float roi_y  = s_io[tid * 7 + 1];
        const float roi_z  = s_io[tid * 7 + 2];
        const float roi_ry = s_io[tid * 7 + 6];
        float pos_y = roi_y + v[48];

        // heading argmax: cols 49..60 -> residual 61..72
        float br = v[49]; int rb = 0; float rres = v[61];
        #pragma unroll
        for (int c2 = 1; c2 < NHB; c2++) {
            if (v[49 + c2] > br) { br = v[49 + c2]; rb = c2; rres = v[61 + c2]; }
        }
        const float APC    = 0.52359877559829887f;   // 2*pi/12
        const float TWO_PI = 6.28318530717958648f;
        const float PI_F   = 3.14159265358979324f;
        float ry = (float)rb * APC + rres * (APC * 0.5f);
        ry = fmodf(ry, TWO_PI);
        if (ry < 0.f) ry += TWO_PI;        // floor-mod (jnp %)
        if (ry > PI_F) ry -= TWO_PI;

        const float hh = v[73] * a0 + a0;
        const float ww = v[74] * a1 + a1;
        const float ll = v[75] * a2 + a2;

        const float cc = cosf(roi_ry);
        const float ss = -sinf(roi_ry);
        const float x_rot = pos_x * cc - pos_z * ss;
        const float z_rot = pos_x * ss + pos_z * cc;

        r0 = x_rot + roi_x;
        r1 = pos_y;
        r2 = z_rot + roi_z;
        r3 = hh; r4 = ww; r5 = ll;
        r6 = ry + roi_ry;
    }

    __syncthreads();   // s_io reads done; reuse as out staging

    if (tid < rows) {
        float* w = s_io + tid * 7;   // dword stride 7: conflict-free
        w[0] = r0; w[1] = r1; w[2] = r2; w[3] = r3; w[4] = r4; w[5] = r5; w[6] = r6;
    }

    __syncthreads();

    // coalesced float4 store of the out tile
    const int nrf = rows * 7;
    const int nr4 = nrf >> 2;
    float* gout = out + row0 * 7;
    float4* go4 = (float4*)gout;
    for (int i = tid; i < nr4; i += BLOCK) go4[i] = si4[i];
    for (int i = (nr4 << 2) + tid; i < nrf; i += BLOCK) gout[i] = s_io[i];
}

} // namespace

extern "C" void kernel_launch(void* const* d_in, const int* in_sizes, int n_in,
                              void* d_out, int out_size, void* d_ws, size_t ws_size,
                              hipStream_t stream) {
    const float* roi    = (const float*)d_in[0];   // (N,7) f32
    const float* pred   = (const float*)d_in[1];   // (N,76) f32
    const float* anchor = (const float*)d_in[2];   // (3,) f32
    float* out = (float*)d_out;                    // (N,7) f32

    const int n = in_sizes[0] / 7;
    const int grid = (n + ROWS - 1) / ROWS;
    decode_kernel<<<grid, BLOCK, 0, stream>>>(roi, pred, anchor, out, n);
}